// Round 1
// baseline (254.418 us; speedup 1.0000x reference)
//
#include <hip/hip_runtime.h>
#include <math.h>

#define DIM 160
#define NB 2
#define BX 32
#define BY 8
#define BZ 8
#define HX (BX + 2)
#define HY (BY + 2)
#define HZ (BZ + 2)
#define NTHREADS 256
#define EPS_F 1.1920928955078125e-07f

// ws layout (doubles):
// [0..1]  sum_mask[n]
// [2..3]  sum_norm_pred[n]   (norm * mask)
// [4..5]  sum_norm_target[n]
// [6]     sum inner^2 (global)
// [8..9]  c_pred[n]   = auto_eps_p^2 + EPS
// [10..11] c_target[n] = auto_eps_t^2 + EPS

__device__ __forceinline__ void sobel3(const float (&s)[HZ][HY][HX], int z, int y, int x,
                                       float& gx, float& gy, float& gz) {
  float Sx[3][3], Dx[3][3];
#pragma unroll
  for (int dz = 0; dz < 3; ++dz) {
#pragma unroll
    for (int dy = 0; dy < 3; ++dy) {
      float a = s[z + dz - 1][y + dy - 1][x - 1];
      float b = s[z + dz - 1][y + dy - 1][x];
      float c = s[z + dz - 1][y + dy - 1][x + 1];
      Sx[dz][dy] = a + 2.0f * b + c;
      Dx[dz][dy] = c - a;
    }
  }
  gx = (Dx[0][0] + 2.0f * Dx[0][1] + Dx[0][2])
     + 2.0f * (Dx[1][0] + 2.0f * Dx[1][1] + Dx[1][2])
     + (Dx[2][0] + 2.0f * Dx[2][1] + Dx[2][2]);
  gy = (Sx[0][2] - Sx[0][0]) + 2.0f * (Sx[1][2] - Sx[1][0]) + (Sx[2][2] - Sx[2][0]);
  float s0 = Sx[0][0] + 2.0f * Sx[0][1] + Sx[0][2];
  float s2 = Sx[2][0] + 2.0f * Sx[2][1] + Sx[2][2];
  gz = s2 - s0;
}

// Load both image tiles (with zero halo) into LDS.
__device__ __forceinline__ void load_tiles(const float* __restrict__ a,
                                           const float* __restrict__ b,
                                           float (&sa)[HZ][HY][HX],
                                           float (&sb)[HZ][HY][HX],
                                           size_t base, int x0, int y0, int z0) {
  for (int i = threadIdx.x; i < HZ * HY * HX; i += NTHREADS) {
    int lx = i % HX;
    int r = i / HX;
    int ly = r % HY;
    int lz = r / HY;
    int gx = x0 + lx - 1, gy = y0 + ly - 1, gz = z0 + lz - 1;
    float va = 0.f, vb = 0.f;
    if ((unsigned)gx < DIM && (unsigned)gy < DIM && (unsigned)gz < DIM) {
      size_t idx = base + ((size_t)gz * DIM + gy) * DIM + gx;
      va = a[idx];
      vb = b[idx];
    }
    sa[lz][ly][lx] = va;
    sb[lz][ly][lx] = vb;
  }
}

__global__ __launch_bounds__(NTHREADS)
void pass1_kernel(const float* __restrict__ pred, const float* __restrict__ tgt,
                  const float* __restrict__ mask, double* __restrict__ ws) {
  __shared__ float sp[HZ][HY][HX];
  __shared__ float st[HZ][HY][HX];
  __shared__ float red[3][4];
  const int tid = threadIdx.x;
  const int n = blockIdx.z / (DIM / BZ);
  const int zt = blockIdx.z % (DIM / BZ);
  const int x0 = blockIdx.x * BX, y0 = blockIdx.y * BY, z0 = zt * BZ;
  const size_t base = (size_t)n * DIM * DIM * DIM;

  load_tiles(pred, tgt, sp, st, base, x0, y0, z0);
  __syncthreads();

  const int tx = tid & (BX - 1);
  const int ty = (tid >> 5) & (BY - 1);
  float acc_m = 0.f, acc_np = 0.f, acc_nt = 0.f;
#pragma unroll
  for (int tz = 0; tz < BZ; ++tz) {
    float gxp, gyp, gzp, gxt, gyt, gzt;
    sobel3(sp, tz + 1, ty + 1, tx + 1, gxp, gyp, gzp);
    sobel3(st, tz + 1, ty + 1, tx + 1, gxt, gyt, gzt);
    size_t idx = base + ((size_t)(z0 + tz) * DIM + (y0 + ty)) * DIM + (x0 + tx);
    float m = mask[idx];
    acc_m += m;
    acc_np += sqrtf(gxp * gxp + gyp * gyp + gzp * gzp + EPS_F) * m;
    acc_nt += sqrtf(gxt * gxt + gyt * gyt + gzt * gzt + EPS_F) * m;
  }

  float v0 = acc_m, v1 = acc_np, v2 = acc_nt;
#pragma unroll
  for (int off = 32; off > 0; off >>= 1) {
    v0 += __shfl_down(v0, off, 64);
    v1 += __shfl_down(v1, off, 64);
    v2 += __shfl_down(v2, off, 64);
  }
  int lane = tid & 63, wave = tid >> 6;
  if (lane == 0) { red[0][wave] = v0; red[1][wave] = v1; red[2][wave] = v2; }
  __syncthreads();
  if (tid == 0) {
    double tm = (double)(red[0][0] + red[0][1] + red[0][2] + red[0][3]);
    double tp = (double)(red[1][0] + red[1][1] + red[1][2] + red[1][3]);
    double tt = (double)(red[2][0] + red[2][1] + red[2][2] + red[2][3]);
    atomicAdd(&ws[0 + n], tm);
    atomicAdd(&ws[2 + n], tp);
    atomicAdd(&ws[4 + n], tt);
  }
}

__global__ void compute_c_kernel(double* __restrict__ ws) {
  if (threadIdx.x == 0 && blockIdx.x == 0) {
    for (int n = 0; n < NB; ++n) {
      double inv_m = 1.0 / ws[0 + n];
      double ae_p = ws[2 + n] * inv_m;  // eta = 1.0
      double ae_t = ws[4 + n] * inv_m;
      ws[8 + n] = ae_p * ae_p + (double)EPS_F;
      ws[10 + n] = ae_t * ae_t + (double)EPS_F;
    }
  }
}

__global__ __launch_bounds__(NTHREADS)
void pass2_kernel(const float* __restrict__ pred, const float* __restrict__ tgt,
                  double* __restrict__ ws) {
  __shared__ float sp[HZ][HY][HX];
  __shared__ float st[HZ][HY][HX];
  __shared__ float red[4];
  const int tid = threadIdx.x;
  const int n = blockIdx.z / (DIM / BZ);
  const int zt = blockIdx.z % (DIM / BZ);
  const int x0 = blockIdx.x * BX, y0 = blockIdx.y * BY, z0 = zt * BZ;
  const size_t base = (size_t)n * DIM * DIM * DIM;

  const float cp = (float)ws[8 + n];
  const float ct = (float)ws[10 + n];

  load_tiles(pred, tgt, sp, st, base, x0, y0, z0);
  __syncthreads();

  const int tx = tid & (BX - 1);
  const int ty = (tid >> 5) & (BY - 1);
  float acc = 0.f;
#pragma unroll
  for (int tz = 0; tz < BZ; ++tz) {
    float gxp, gyp, gzp, gxt, gyt, gzt;
    sobel3(sp, tz + 1, ty + 1, tx + 1, gxp, gyp, gzp);
    sobel3(st, tz + 1, ty + 1, tx + 1, gxt, gyt, gzt);
    float sqp = gxp * gxp + gyp * gyp + gzp * gzp;
    float sqt = gxt * gxt + gyt * gyt + gzt * gzt;
    float dot = gxp * gxt + gyp * gyt + gzp * gzt;
    float inner = dot * rsqrtf((sqp + cp) * (sqt + ct));
    acc += inner * inner;
  }

#pragma unroll
  for (int off = 32; off > 0; off >>= 1) acc += __shfl_down(acc, off, 64);
  int lane = tid & 63, wave = tid >> 6;
  if (lane == 0) red[wave] = acc;
  __syncthreads();
  if (tid == 0) {
    double t = (double)(red[0] + red[1] + red[2] + red[3]);
    atomicAdd(&ws[6], t);
  }
}

__global__ void finalize_kernel(const double* __restrict__ ws, float* __restrict__ out) {
  if (threadIdx.x == 0 && blockIdx.x == 0) {
    double mean = ws[6] / (double)((double)NB * DIM * DIM * DIM);
    out[0] = (float)(1.0 - mean);
  }
}

extern "C" void kernel_launch(void* const* d_in, const int* in_sizes, int n_in,
                              void* d_out, int out_size, void* d_ws, size_t ws_size,
                              hipStream_t stream) {
  const float* pred = (const float*)d_in[0];
  const float* tgt = (const float*)d_in[1];
  const float* mask = (const float*)d_in[2];
  float* out = (float*)d_out;
  double* ws = (double*)d_ws;

  hipMemsetAsync(d_ws, 0, 16 * sizeof(double), stream);

  dim3 grid(DIM / BX, DIM / BY, (DIM / BZ) * NB);
  pass1_kernel<<<grid, NTHREADS, 0, stream>>>(pred, tgt, mask, ws);
  compute_c_kernel<<<1, 64, 0, stream>>>(ws);
  pass2_kernel<<<grid, NTHREADS, 0, stream>>>(pred, tgt, ws);
  finalize_kernel<<<1, 64, 0, stream>>>(ws, out);
}

// Round 2
// 127.557 us; speedup vs baseline: 1.9945x; 1.9945x over previous
//
#include <hip/hip_runtime.h>
#include <math.h>

#define DIM 160
#define NB 2
#define BX 32          // tile width (x), 4 voxels per thread
#define BY 32          // tile height (y), 1 voxel per thread row
#define VX 4
#define TX (BX / VX)   // 8 threads in x
#define NTHREADS (TX * BY)  // 256
#define PLW 36         // plane cols: 2 + 32 + 2 (aligned halo)
#define PLH 34         // plane rows: 1 + 32 + 1
#define PLN (PLW * PLH)     // 1224
#define CHUNK 10
#define NCH (DIM / CHUNK)   // 16
#define EPS_F 1.1920928955078125e-07f

// ws layout (doubles):
// [0..1] sum_mask[n], [2..3] sum_norm_pred[n], [4..5] sum_norm_tgt[n],
// [6] sum inner^2, [8..9] c_pred[n], [10..11] c_tgt[n]

__device__ __forceinline__ void load_plane_regs(const float* __restrict__ a,
                                                const float* __restrict__ b,
                                                size_t base, int x0, int y0, int z,
                                                int tid, float (&ra)[5], float (&rb)[5]) {
#pragma unroll
  for (int k = 0; k < 5; ++k) {
    ra[k] = 0.f; rb[k] = 0.f;
    int i = tid + k * NTHREADS;
    if (i < PLN && (unsigned)z < DIM) {
      int ly = i / PLW, lx = i - ly * PLW;
      int gy = y0 - 1 + ly, gx = x0 - 2 + lx;
      if ((unsigned)gy < DIM && (unsigned)gx < DIM) {
        size_t idx = base + ((size_t)z * DIM + gy) * DIM + gx;
        ra[k] = a[idx]; rb[k] = b[idx];
      }
    }
  }
}

__device__ __forceinline__ void store_plane(float* __restrict__ p0, float* __restrict__ p1,
                                            int tid, const float (&ra)[5], const float (&rb)[5]) {
#pragma unroll
  for (int k = 0; k < 5; ++k) {
    int i = tid + k * NTHREADS;
    if (i < PLN) { p0[i] = ra[k]; p1[i] = rb[k]; }
  }
}

// P1 = diff_x*smooth_y, P2 = smooth_x*diff_y, P3 = smooth_x*smooth_y  (per voxel)
__device__ __forceinline__ void compute_P(const float* __restrict__ pl, int tx, int ty,
                                          float (&p1)[VX], float (&p2)[VX], float (&p3)[VX]) {
  float Sx[3][VX], Dx[3][VX];
#pragma unroll
  for (int r = 0; r < 3; ++r) {
    const float4* row = (const float4*)(pl + (ty + r) * PLW + tx * 4);
    float4 f0 = row[0], f1 = row[1];
    float f[8] = {f0.x, f0.y, f0.z, f0.w, f1.x, f1.y, f1.z, f1.w};
#pragma unroll
    for (int j = 0; j < VX; ++j) {
      Sx[r][j] = f[j + 1] + 2.f * f[j + 2] + f[j + 3];
      Dx[r][j] = f[j + 3] - f[j + 1];
    }
  }
#pragma unroll
  for (int j = 0; j < VX; ++j) {
    p1[j] = Dx[0][j] + 2.f * Dx[1][j] + Dx[2][j];
    p2[j] = Sx[2][j] - Sx[0][j];
    p3[j] = Sx[0][j] + 2.f * Sx[1][j] + Sx[2][j];
  }
}

__global__ __launch_bounds__(NTHREADS)
void pass1_kernel(const float* __restrict__ pred, const float* __restrict__ tgt,
                  const float* __restrict__ mask, double* __restrict__ ws) {
  __shared__ __align__(16) float lds[2][2][PLN];
  __shared__ float red[3][4];
  const int tid = threadIdx.x;
  const int tx = tid % TX, ty = tid / TX;
  const int n = blockIdx.z / NCH, ch = blockIdx.z % NCH;
  const int x0 = blockIdx.x * BX, y0 = blockIdx.y * BY;
  const int zs = ch * CHUNK;
  const size_t base = (size_t)n * DIM * DIM * DIM;

  float A[2][3][VX], B[2][3][VX];
#pragma unroll
  for (int im = 0; im < 2; ++im)
#pragma unroll
    for (int f = 0; f < 3; ++f)
#pragma unroll
      for (int j = 0; j < VX; ++j) { A[im][f][j] = 0.f; B[im][f][j] = 0.f; }

  float acc_m = 0.f, acc_np = 0.f, acc_nt = 0.f;
  float ra[5], rb[5];

  load_plane_regs(pred, tgt, base, x0, y0, zs - 1, tid, ra, rb);

  for (int z = zs - 1; z <= zs + CHUNK; ++z) {
    const int b = (z - (zs - 1)) & 1;
    store_plane(&lds[b][0][0], &lds[b][1][0], tid, ra, rb);
    if (z < zs + CHUNK) load_plane_regs(pred, tgt, base, x0, y0, z + 1, tid, ra, rb);
    __syncthreads();

    float P[2][3][VX];
#pragma unroll
    for (int im = 0; im < 2; ++im)
      compute_P(&lds[b][im][0], tx, ty, P[im][0], P[im][1], P[im][2]);

    if (z > zs) {
      const int zo = z - 1;
      const float4 mv = *(const float4*)(mask + base + ((size_t)zo * DIM + (y0 + ty)) * DIM + x0 + 4 * tx);
      float m4[4] = {mv.x, mv.y, mv.z, mv.w};
      float np[VX], nt[VX];
#pragma unroll
      for (int im = 0; im < 2; ++im)
#pragma unroll
        for (int j = 0; j < VX; ++j) {
          float gx = B[im][0][j] + 2.f * A[im][0][j] + P[im][0][j];
          float gy = B[im][1][j] + 2.f * A[im][1][j] + P[im][1][j];
          float gz = P[im][2][j] - B[im][2][j];
          float nrm = sqrtf(gx * gx + gy * gy + gz * gz + EPS_F);
          if (im == 0) np[j] = nrm; else nt[j] = nrm;
        }
#pragma unroll
      for (int j = 0; j < VX; ++j) {
        acc_m += m4[j];
        acc_np += np[j] * m4[j];
        acc_nt += nt[j] * m4[j];
      }
    }
#pragma unroll
    for (int im = 0; im < 2; ++im)
#pragma unroll
      for (int f = 0; f < 3; ++f)
#pragma unroll
        for (int j = 0; j < VX; ++j) { B[im][f][j] = A[im][f][j]; A[im][f][j] = P[im][f][j]; }
  }

  float v0 = acc_m, v1 = acc_np, v2 = acc_nt;
#pragma unroll
  for (int off = 32; off > 0; off >>= 1) {
    v0 += __shfl_down(v0, off, 64);
    v1 += __shfl_down(v1, off, 64);
    v2 += __shfl_down(v2, off, 64);
  }
  int lane = tid & 63, wave = tid >> 6;
  if (lane == 0) { red[0][wave] = v0; red[1][wave] = v1; red[2][wave] = v2; }
  __syncthreads();
  if (tid == 0) {
    atomicAdd(&ws[0 + n], (double)(red[0][0] + red[0][1] + red[0][2] + red[0][3]));
    atomicAdd(&ws[2 + n], (double)(red[1][0] + red[1][1] + red[1][2] + red[1][3]));
    atomicAdd(&ws[4 + n], (double)(red[2][0] + red[2][1] + red[2][2] + red[2][3]));
  }
}

__global__ void compute_c_kernel(double* __restrict__ ws) {
  if (threadIdx.x == 0 && blockIdx.x == 0) {
    for (int n = 0; n < NB; ++n) {
      double inv_m = 1.0 / ws[0 + n];
      double ae_p = ws[2 + n] * inv_m;  // eta = 1.0
      double ae_t = ws[4 + n] * inv_m;
      ws[8 + n] = ae_p * ae_p + (double)EPS_F;
      ws[10 + n] = ae_t * ae_t + (double)EPS_F;
    }
  }
}

__global__ __launch_bounds__(NTHREADS)
void pass2_kernel(const float* __restrict__ pred, const float* __restrict__ tgt,
                  double* __restrict__ ws) {
  __shared__ __align__(16) float lds[2][2][PLN];
  __shared__ float red[4];
  const int tid = threadIdx.x;
  const int tx = tid % TX, ty = tid / TX;
  const int n = blockIdx.z / NCH, ch = blockIdx.z % NCH;
  const int x0 = blockIdx.x * BX, y0 = blockIdx.y * BY;
  const int zs = ch * CHUNK;
  const size_t base = (size_t)n * DIM * DIM * DIM;

  const float cp = (float)ws[8 + n];
  const float ct = (float)ws[10 + n];

  float A[2][3][VX], B[2][3][VX];
#pragma unroll
  for (int im = 0; im < 2; ++im)
#pragma unroll
    for (int f = 0; f < 3; ++f)
#pragma unroll
      for (int j = 0; j < VX; ++j) { A[im][f][j] = 0.f; B[im][f][j] = 0.f; }

  float acc = 0.f;
  float ra[5], rb[5];

  load_plane_regs(pred, tgt, base, x0, y0, zs - 1, tid, ra, rb);

  for (int z = zs - 1; z <= zs + CHUNK; ++z) {
    const int b = (z - (zs - 1)) & 1;
    store_plane(&lds[b][0][0], &lds[b][1][0], tid, ra, rb);
    if (z < zs + CHUNK) load_plane_regs(pred, tgt, base, x0, y0, z + 1, tid, ra, rb);
    __syncthreads();

    float P[2][3][VX];
#pragma unroll
    for (int im = 0; im < 2; ++im)
      compute_P(&lds[b][im][0], tx, ty, P[im][0], P[im][1], P[im][2]);

    if (z > zs) {
#pragma unroll
      for (int j = 0; j < VX; ++j) {
        float gpx = B[0][0][j] + 2.f * A[0][0][j] + P[0][0][j];
        float gpy = B[0][1][j] + 2.f * A[0][1][j] + P[0][1][j];
        float gpz = P[0][2][j] - B[0][2][j];
        float gtx = B[1][0][j] + 2.f * A[1][0][j] + P[1][0][j];
        float gty = B[1][1][j] + 2.f * A[1][1][j] + P[1][1][j];
        float gtz = P[1][2][j] - B[1][2][j];
        float sqp = gpx * gpx + gpy * gpy + gpz * gpz;
        float sqt = gtx * gtx + gty * gty + gtz * gtz;
        float dot = gpx * gtx + gpy * gty + gpz * gtz;
        float inner = dot * rsqrtf((sqp + cp) * (sqt + ct));
        acc += inner * inner;
      }
    }
#pragma unroll
    for (int im = 0; im < 2; ++im)
#pragma unroll
      for (int f = 0; f < 3; ++f)
#pragma unroll
        for (int j = 0; j < VX; ++j) { B[im][f][j] = A[im][f][j]; A[im][f][j] = P[im][f][j]; }
  }

#pragma unroll
  for (int off = 32; off > 0; off >>= 1) acc += __shfl_down(acc, off, 64);
  int lane = tid & 63, wave = tid >> 6;
  if (lane == 0) red[wave] = acc;
  __syncthreads();
  if (tid == 0) atomicAdd(&ws[6], (double)(red[0] + red[1] + red[2] + red[3]));
}

__global__ void finalize_kernel(const double* __restrict__ ws, float* __restrict__ out) {
  if (threadIdx.x == 0 && blockIdx.x == 0) {
    double mean = ws[6] / ((double)NB * DIM * DIM * DIM);
    out[0] = (float)(1.0 - mean);
  }
}

extern "C" void kernel_launch(void* const* d_in, const int* in_sizes, int n_in,
                              void* d_out, int out_size, void* d_ws, size_t ws_size,
                              hipStream_t stream) {
  const float* pred = (const float*)d_in[0];
  const float* tgt = (const float*)d_in[1];
  const float* mask = (const float*)d_in[2];
  float* out = (float*)d_out;
  double* ws = (double*)d_ws;

  hipMemsetAsync(d_ws, 0, 16 * sizeof(double), stream);

  dim3 grid(DIM / BX, DIM / BY, NCH * NB);
  pass1_kernel<<<grid, NTHREADS, 0, stream>>>(pred, tgt, mask, ws);
  compute_c_kernel<<<1, 64, 0, stream>>>(ws);
  pass2_kernel<<<grid, NTHREADS, 0, stream>>>(pred, tgt, ws);
  finalize_kernel<<<1, 64, 0, stream>>>(ws, out);
}